// Round 4
// baseline (239.756 us; speedup 1.0000x reference)
//
#include <hip/hip_runtime.h>
#include <cstdint>
#include <math.h>

#define DEV __device__ __forceinline__

typedef unsigned int u32;
typedef unsigned short u16;
typedef __attribute__((ext_vector_type(4))) float f32x4;
typedef __attribute__((ext_vector_type(4))) u32 u32x4;
typedef __attribute__((ext_vector_type(2))) u32 u32x2;
typedef __attribute__((ext_vector_type(8))) __bf16 bf16x8;

static_assert(sizeof(bf16x8) == 16, "bf16x8 must be 16B");

static constexpr int Tn = 2048, Cn = 1024;
static constexpr int Mrows = 2 * Tn;  // 4096
// Q scale: 1/sqrt(64)/TEMP * log2(e)  (softmax runs in exp2 domain)
static constexpr float QSCALE2 = 0.125f * 1.44269504088896f;

DEV u16 f2bf_rne(float f) {
  u32 u = __builtin_bit_cast(u32, f);
  u32 r = u + 0x7fffu + ((u >> 16) & 1u);
  return (u16)(r >> 16);
}
DEV float bf2f(u16 h) {
  u32 u = ((u32)h) << 16;
  return __builtin_bit_cast(float, u);
}
DEV u32 pack2bf(float a, float b) {  // a -> low16, b -> high16
  return (u32)f2bf_rne(a) | ((u32)f2bf_rne(b) << 16);
}
DEV float fexp2(float x) {
#if __has_builtin(__builtin_amdgcn_exp2f)
  return __builtin_amdgcn_exp2f(x);
#else
  return exp2f(x);
#endif
}

// async 16B global->LDS (wave-uniform base + lane*16 on the LDS side)
DEV void stage16(const void* g, void* l) {
#if __has_builtin(__builtin_amdgcn_global_load_lds)
  __builtin_amdgcn_global_load_lds(
      (__attribute__((address_space(1))) u32*)(uintptr_t)g,
      (__attribute__((address_space(3))) u32*)l, 16, 0, 0);
#else
  *(u32x4*)l = *(const u32x4*)g;
#endif
}

// ---------------- LayerNorm (fp32 in -> bf16 out) ----------------
__global__ __launch_bounds__(256) void ln_kernel(const float* __restrict__ x,
                                                 const float* __restrict__ sc,
                                                 const float* __restrict__ bi,
                                                 u16* __restrict__ xn) {
  int row = blockIdx.x;
  int t = threadIdx.x;
  const float* xr = x + (size_t)row * Cn;
  f32x4 v = *(const f32x4*)(xr + t * 4);
  float s = v.x + v.y + v.z + v.w;
  float s2 = v.x * v.x + v.y * v.y + v.z * v.z + v.w * v.w;
#pragma unroll
  for (int off = 1; off < 64; off <<= 1) {
    s += __shfl_xor(s, off);
    s2 += __shfl_xor(s2, off);
  }
  __shared__ float red[8];
  if ((t & 63) == 0) {
    red[(t >> 6) * 2] = s;
    red[(t >> 6) * 2 + 1] = s2;
  }
  __syncthreads();
  s = red[0] + red[2] + red[4] + red[6];
  s2 = red[1] + red[3] + red[5] + red[7];
  float mean = s * (1.0f / Cn);
  float var = s2 * (1.0f / Cn) - mean * mean;
  float rstd = rsqrtf(var + 1e-6f);
  f32x4 g = *(const f32x4*)(sc + t * 4);
  f32x4 b = *(const f32x4*)(bi + t * 4);
  u32 lo = pack2bf((v.x - mean) * rstd * g.x + b.x, (v.y - mean) * rstd * g.y + b.y);
  u32 hi = pack2bf((v.z - mean) * rstd * g.z + b.z, (v.w - mean) * rstd * g.w + b.w);
  u32x2 pack = {lo, hi};
  *(u32x2*)(xn + (size_t)row * Cn + t * 4) = pack;
}

// -------- transpose + cast both weights: fp32 [1024][Cc] -> bf16 [Cc][1024] --
__global__ __launch_bounds__(256) void transpose_cast2(const float* __restrict__ qkv_w,
                                                       u16* __restrict__ wqkv,
                                                       const float* __restrict__ proj_w,
                                                       u16* __restrict__ wproj) {
  __shared__ float tile[32][33];
  int bx = blockIdx.x;
  const float* src;
  u16* dst;
  int Cc;
  if (bx < 96) {
    src = qkv_w; dst = wqkv; Cc = 3072;
  } else {
    src = proj_w; dst = wproj; Cc = 1024; bx -= 96;
  }
  int tx = threadIdx.x, ty = threadIdx.y;
  int c0 = bx * 32, r0 = blockIdx.y * 32;
#pragma unroll
  for (int k = 0; k < 4; ++k)
    tile[ty + 8 * k][tx] = src[(size_t)(r0 + ty + 8 * k) * Cc + c0 + tx];
  __syncthreads();
#pragma unroll
  for (int k = 0; k < 4; ++k)
    dst[(size_t)(c0 + ty + 8 * k) * 1024 + r0 + tx] = f2bf_rne(tile[tx][ty + 8 * k]);
}

// ---- V^T prepass: qkvm V region [token][h*64+d] -> vt[bh][d][t] bf16 ----
__global__ __launch_bounds__(256) void vt_prep(const u16* __restrict__ qkvm,
                                               u16* __restrict__ vt) {
  __shared__ u16 tile[32][33];
  int bh = blockIdx.z;
  int b = bh >> 4, h = bh & 15;
  int t0 = blockIdx.x * 32, d0 = blockIdx.y * 32;
  int tx = threadIdx.x, ty = threadIdx.y;
#pragma unroll
  for (int k = 0; k < 4; ++k)
    tile[ty + 8 * k][tx] =
        qkvm[(size_t)(b * Tn + t0 + ty + 8 * k) * 3072 + 2 * Cn + h * 64 + d0 + tx];
  __syncthreads();
#pragma unroll
  for (int k = 0; k < 4; ++k)
    vt[((size_t)bh * 64 + d0 + ty + 8 * k) * 2048 + t0 + tx] = tile[tx][ty + 8 * k];
}

// ---------------- GEMM: A bf16 [M][K] x Bt bf16 [N][K] + bias -> C [M][N] ----
template <bool OUT_F32, bool QKV_SCALE>
__global__ __launch_bounds__(256, 3) void gemm_kernel(const u16* __restrict__ A,
                                                      const u16* __restrict__ Bt,
                                                      const float* __restrict__ bias,
                                                      void* __restrict__ Cout,
                                                      int Nsz, int Ksz) {
  __shared__ u16 As[128 * 32];
  __shared__ u16 Bs[128 * 32];
  int t = threadIdx.x;
  int l = t & 63, w = t >> 6;
  int quad = l >> 4, c16 = l & 15;
  int wm = w & 1, wn = w >> 1;
  int m0 = blockIdx.y * 128, n0 = blockIdx.x * 128;

  f32x4 acc[4][4];
#pragma unroll
  for (int mt = 0; mt < 4; ++mt)
#pragma unroll
    for (int nt = 0; nt < 4; ++nt) acc[mt][nt] = (f32x4){0.f, 0.f, 0.f, 0.f};

  for (int kk = 0; kk < Ksz; kk += 32) {
#pragma unroll
    for (int i = 0; i < 2; ++i) {
      int c = t + i * 256;
      int m = c >> 2, k8 = (c & 3) ^ ((m >> 1) & 3);
      stage16(A + (size_t)(m0 + m) * Ksz + kk + k8 * 8, (char*)As + c * 16);
    }
#pragma unroll
    for (int i = 0; i < 2; ++i) {
      int c = t + i * 256;
      int n = c >> 2, k8 = (c & 3) ^ ((n >> 1) & 3);
      stage16(Bt + (size_t)(n0 + n) * Ksz + kk + k8 * 8, (char*)Bs + c * 16);
    }
    __syncthreads();
    bf16x8 af[4], bf[4];
#pragma unroll
    for (int mt = 0; mt < 4; ++mt) {
      int m = wm * 64 + mt * 16 + c16;
      int LC = m * 4 + (quad ^ ((m >> 1) & 3));
      af[mt] = *(const bf16x8*)((const char*)As + LC * 16);
    }
#pragma unroll
    for (int nt = 0; nt < 4; ++nt) {
      int n = wn * 64 + nt * 16 + c16;
      int LC = n * 4 + (quad ^ ((n >> 1) & 3));
      bf[nt] = *(const bf16x8*)((const char*)Bs + LC * 16);
    }
#pragma unroll
    for (int mt = 0; mt < 4; ++mt)
#pragma unroll
      for (int nt = 0; nt < 4; ++nt)
        acc[mt][nt] = __builtin_amdgcn_mfma_f32_16x16x32_bf16(af[mt], bf[nt],
                                                              acc[mt][nt], 0, 0, 0);
    __syncthreads();
  }
  // epilogue: C/D layout col=lane&15, row=quad*4+reg
#pragma unroll
  for (int mt = 0; mt < 4; ++mt) {
    int row = m0 + wm * 64 + mt * 16 + quad * 4;
#pragma unroll
    for (int nt = 0; nt < 4; ++nt) {
      int col = n0 + wn * 64 + nt * 16 + c16;
      float bv = bias[col];
      float scale = (QKV_SCALE && col < 1024) ? QSCALE2 : 1.0f;
#pragma unroll
      for (int r = 0; r < 4; ++r) {
        float v = (acc[mt][nt][r] + bv) * scale;
        if (OUT_F32)
          ((float*)Cout)[(size_t)(row + r) * Nsz + col] = v;
        else
          ((u16*)Cout)[(size_t)(row + r) * Nsz + col] = f2bf_rne(v);
      }
    }
  }
}

// ---------------- causal flash attention, balanced chunks ----------------
// chunk table: {qt, k0, kcnt, half} sorted by kcnt desc; half<0 = direct write
__constant__ int4 chunk_tab[24] = {
    {15, 0, 8, 0}, {15, 8, 8, 1}, {14, 0, 8, 0}, {7, 0, 8, -1},
    {14, 8, 7, 1}, {13, 0, 7, 0}, {13, 7, 7, 1}, {12, 0, 7, 0}, {6, 0, 7, -1},
    {12, 7, 6, 1}, {11, 0, 6, 0}, {11, 6, 6, 1}, {10, 0, 6, 0}, {5, 0, 6, -1},
    {10, 6, 5, 1}, {9, 0, 5, 0}, {9, 5, 5, 1}, {8, 0, 5, 0}, {4, 0, 5, -1},
    {8, 5, 4, 1}, {3, 0, 4, -1},
    {2, 0, 3, -1},
    {1, 0, 2, -1},
    {0, 0, 1, -1}};

// qkv bf16 [4096][3072] (Q pre-scaled by 0.125*log2e), vt bf16 [32][64][2048]
// -> attn bf16 [4096][1024] (direct) or partials Op/ml. Softmax in exp2 domain.
__global__ __launch_bounds__(256, 3) void flash_kernel(const u16* __restrict__ qkv,
                                                       const u16* __restrict__ vt,
                                                       u16* __restrict__ aout,
                                                       u16* __restrict__ Op,
                                                       float* __restrict__ ml) {
  int4 ck = chunk_tab[blockIdx.x >> 5];
  int bh = blockIdx.x & 31;
  int qt = ck.x, k0 = ck.y, kend = ck.y + ck.z, half = ck.w;
  int b = bh >> 4, h = bh & 15;
  int t = threadIdx.x, l = t & 63, w = t >> 6;
  int quad = l >> 4, c16 = l & 15;
  int q0 = qt * 128;

  __shared__ u16 Ks[128 * 64];  // [key][d] swizzled 16B chunks (16 KiB)
  __shared__ u16 Vs[64 * 128];  // [d][key] swizzled 16B chunks (16 KiB)
  __shared__ u16 Ps[128 * 64];  // [q][key-half] 16B chunks, wave-private (16 KiB)

  // Q fragments (B-operand layout), pre-scaled in GEMM epilogue
  bf16x8 qf[2][2];
#pragma unroll
  for (int nt = 0; nt < 2; ++nt)
#pragma unroll
    for (int ks = 0; ks < 2; ++ks)
      qf[nt][ks] = *(const bf16x8*)(qkv +
          (size_t)(b * Tn + q0 + w * 32 + nt * 16 + c16) * 3072 +
          h * 64 + ks * 32 + quad * 8);

  float mrow[2] = {-1e30f, -1e30f};
  float lrow[2] = {0.f, 0.f};
  f32x4 o[2][4];
#pragma unroll
  for (int mq = 0; mq < 2; ++mq)
#pragma unroll
    for (int dt = 0; dt < 4; ++dt) o[mq][dt] = (f32x4){0.f, 0.f, 0.f, 0.f};

  for (int kt = k0; kt < kend; ++kt) {
    // stage K [128key][64d] (async, swizzled)
#pragma unroll
    for (int i = 0; i < 4; ++i) {
      int c = t + i * 256;
      int key = c >> 3, d8 = (c & 7) ^ (key & 7);
      stage16(qkv + (size_t)(b * Tn + kt * 128 + key) * 3072 + Cn + h * 64 + d8 * 8,
              (char*)Ks + c * 16);
    }
    // stage V^T [64d][128key] (async, swizzled)
#pragma unroll
    for (int i = 0; i < 4; ++i) {
      int c = t + i * 256;
      int d = c >> 4, k8 = (c & 15) ^ (d & 15);
      stage16(vt + ((size_t)bh * 64 + d) * 2048 + kt * 128 + k8 * 8,
              (char*)Vs + c * 16);
    }
    __syncthreads();

    // S^T = K . Q^T  (A=K from LDS, B=Q^T from regs); m=key, n=q
    f32x4 s[8][2];
#pragma unroll
    for (int mt = 0; mt < 8; ++mt)
#pragma unroll
      for (int nt = 0; nt < 2; ++nt) s[mt][nt] = (f32x4){0.f, 0.f, 0.f, 0.f};
#pragma unroll
    for (int mt = 0; mt < 8; ++mt) {
#pragma unroll
      for (int ks = 0; ks < 2; ++ks) {
        int key = mt * 16 + c16;
        int d8 = ks * 4 + quad;
        int LC = key * 8 + (d8 ^ (key & 7));
        bf16x8 kf = *(const bf16x8*)((const char*)Ks + LC * 16);
#pragma unroll
        for (int nt = 0; nt < 2; ++nt)
          s[mt][nt] = __builtin_amdgcn_mfma_f32_16x16x32_bf16(kf, qf[nt][ks],
                                                              s[mt][nt], 0, 0, 0);
      }
    }
    // diagonal causal mask
    if (kt == qt) {
#pragma unroll
      for (int mt = 0; mt < 8; ++mt)
#pragma unroll
        for (int nt = 0; nt < 2; ++nt)
#pragma unroll
          for (int r = 0; r < 4; ++r) {
            int key = kt * 128 + mt * 16 + quad * 4 + r;
            int q = q0 + w * 32 + nt * 16 + c16;
            if (key > q) s[mt][nt][r] = -1e30f;
          }
    }
    // online softmax, exp2 domain (stats per q = c16, replicated over quads)
    float alph[2];
#pragma unroll
    for (int nt = 0; nt < 2; ++nt) {
      float rm = -1e30f;
#pragma unroll
      for (int mt = 0; mt < 8; ++mt)
#pragma unroll
        for (int r = 0; r < 4; ++r) rm = fmaxf(rm, s[mt][nt][r]);
      rm = fmaxf(rm, __shfl_xor(rm, 16));
      rm = fmaxf(rm, __shfl_xor(rm, 32));
      float mnew = fmaxf(mrow[nt], rm);
      alph[nt] = fexp2(mrow[nt] - mnew);
      mrow[nt] = mnew;
      float rs = 0.f;
#pragma unroll
      for (int mt = 0; mt < 8; ++mt)
#pragma unroll
        for (int r = 0; r < 4; ++r) {
          float e = fexp2(s[mt][nt][r] - mnew);
          s[mt][nt][r] = e;
          rs += e;
        }
      rs += __shfl_xor(rs, 16);
      rs += __shfl_xor(rs, 32);
      lrow[nt] = lrow[nt] * alph[nt] + rs;
    }
    // rescale O by alpha (alpha lives per q=c16; O rows are q=quad*4+r)
#pragma unroll
    for (int mq = 0; mq < 2; ++mq)
#pragma unroll
      for (int r = 0; r < 4; ++r) {
        float a = __shfl(alph[mq], quad * 4 + r);
#pragma unroll
        for (int dt = 0; dt < 4; ++dt) o[mq][dt][r] *= a;
      }
    // PV in two key-halves through 16KB wave-private Ps (same-wave DS is in-order)
#pragma unroll
    for (int ksh = 0; ksh < 2; ++ksh) {
#pragma unroll
      for (int mtl = 0; mtl < 4; ++mtl) {
        int mt = ksh * 4 + mtl;
#pragma unroll
        for (int nt = 0; nt < 2; ++nt) {
          int q = w * 32 + nt * 16 + c16;
          int c8 = mtl * 2 + (quad >> 1);
          u32x2 pk = {pack2bf(s[mt][nt][0], s[mt][nt][1]),
                      pack2bf(s[mt][nt][2], s[mt][nt][3])};
          *(u32x2*)((char*)Ps + q * 128 + ((c8 ^ (c16 & 7)) * 16) + (quad & 1) * 8) =
              pk;
        }
      }
#pragma unroll
      for (int ksl = 0; ksl < 2; ++ksl) {
        int ks = ksh * 2 + ksl;
        bf16x8 pa[2];
#pragma unroll
        for (int mq = 0; mq < 2; ++mq) {
          int q = w * 32 + mq * 16 + c16;
          int c8 = ksl * 4 + quad;
          pa[mq] = *(const bf16x8*)((const char*)Ps + q * 128 +
                                    ((c8 ^ (c16 & 7)) * 16));
        }
#pragma unroll
        for (int dt = 0; dt < 4; ++dt) {
          int d = dt * 16 + c16;
          int vc = d * 16 + ((ks * 4 + quad) ^ (d & 15));
          bf16x8 vf = *(const bf16x8*)((const char*)Vs + vc * 16);
#pragma unroll
          for (int mq = 0; mq < 2; ++mq)
            o[mq][dt] = __builtin_amdgcn_mfma_f32_16x16x32_bf16(pa[mq], vf,
                                                                o[mq][dt], 0, 0, 0);
        }
      }
    }
    __syncthreads();
  }

  float linv[2] = {1.0f / lrow[0], 1.0f / lrow[1]};
  if (half < 0) {
    // direct output
#pragma unroll
    for (int mq = 0; mq < 2; ++mq)
#pragma unroll
      for (int r = 0; r < 4; ++r) {
        float li = __shfl(linv[mq], quad * 4 + r);
        int q = q0 + w * 32 + mq * 16 + quad * 4 + r;
#pragma unroll
        for (int dt = 0; dt < 4; ++dt)
          aout[(size_t)(b * Tn + q) * 1024 + h * 64 + dt * 16 + c16] =
              f2bf_rne(o[mq][dt][r] * li);
      }
  } else {
    // partial: normalized O + (m, l) per row (m in log2 domain)
    int ps = ((qt - 8) * 32 + bh) * 2 + half;
#pragma unroll
    for (int mq = 0; mq < 2; ++mq)
#pragma unroll
      for (int r = 0; r < 4; ++r) {
        float li = __shfl(linv[mq], quad * 4 + r);
        int qr = w * 32 + mq * 16 + quad * 4 + r;
#pragma unroll
        for (int dt = 0; dt < 4; ++dt)
          Op[((size_t)ps * 128 + qr) * 64 + dt * 16 + c16] =
              f2bf_rne(o[mq][dt][r] * li);
      }
    if (quad == 0) {
#pragma unroll
      for (int nt = 0; nt < 2; ++nt) {
        int qr = w * 32 + nt * 16 + c16;
        ml[((size_t)ps * 128 + qr) * 2] = mrow[nt];
        ml[((size_t)ps * 128 + qr) * 2 + 1] = lrow[nt];
      }
    }
  }
}

// ---------------- combine split partials (m in log2 domain) ----------------
__global__ __launch_bounds__(256) void combine_kernel(const u16* __restrict__ Op,
                                                      const float* __restrict__ ml,
                                                      u16* __restrict__ aout) {
  int qt = 8 + (blockIdx.x >> 5);
  int bh = blockIdx.x & 31;
  int b = bh >> 4, h = bh & 15;
  int ps0 = ((qt - 8) * 32 + bh) * 2;
  int d = threadIdx.x & 63, rq = threadIdx.x >> 6;
  for (int r = 0; r < 32; ++r) {
    int row = rq * 32 + r;
    float m0 = ml[((size_t)ps0 * 128 + row) * 2];
    float l0 = ml[((size_t)ps0 * 128 + row) * 2 + 1];
    float m1 = ml[((size_t)(ps0 + 1) * 128 + row) * 2];
    float l1 = ml[((size_t)(ps0 + 1) * 128 + row) * 2 + 1];
    float M = fmaxf(m0, m1);
    float w0 = fexp2(m0 - M) * l0, w1 = fexp2(m1 - M) * l1;
    float inv = 1.0f / (w0 + w1);
    float o0 = bf2f(Op[((size_t)ps0 * 128 + row) * 64 + d]);
    float o1 = bf2f(Op[((size_t)(ps0 + 1) * 128 + row) * 64 + d]);
    aout[(size_t)(b * Tn + qt * 128 + row) * 1024 + h * 64 + d] =
        f2bf_rne((w0 * o0 + w1 * o1) * inv);
  }
}

extern "C" void kernel_launch(void* const* d_in, const int* in_sizes, int n_in,
                              void* d_out, int out_size, void* d_ws, size_t ws_size,
                              hipStream_t stream) {
  const float* x = (const float*)d_in[0];
  // d_in[1] = causal mask: tril, implemented analytically — never read
  const float* ln_s = (const float*)d_in[2];
  const float* ln_b = (const float*)d_in[3];
  const float* qkv_w = (const float*)d_in[4];
  const float* qkv_b = (const float*)d_in[5];
  const float* proj_w = (const float*)d_in[6];
  const float* proj_b = (const float*)d_in[7];
  float* out = (float*)d_out;
  char* ws = (char*)d_ws;

  u16* xn = (u16*)ws;                       // 8 MiB  [4096][1024]
  u16* wqkv = (u16*)(ws + (8ull << 20));    // 6 MiB  [3072][1024]
  u16* wproj = (u16*)(ws + (14ull << 20));  // 2 MiB  [1024][1024]
  u16* qkvm = (u16*)(ws + (16ull << 20));   // 24 MiB [4096][3072]
  u16* attn = (u16*)(ws + (40ull << 20));   // 8 MiB  [4096][1024]
  u16* vt = (u16*)(ws + (48ull << 20));     // 8 MiB  [32][64][2048]
  // partials alias xn/wqkv (dead after QKV GEMM):
  u16* Op = (u16*)ws;                       // 8 MiB  [512][128][64] bf16
  float* ml = (float*)(ws + (8ull << 20));  // 512 KiB [512][128][2] f32

  ln_kernel<<<Mrows, 256, 0, stream>>>(x, ln_s, ln_b, xn);
  transpose_cast2<<<dim3(128, 32), dim3(32, 8), 0, stream>>>(qkv_w, wqkv, proj_w,
                                                             wproj);
  gemm_kernel<false, true><<<dim3(24, 32), 256, 0, stream>>>(xn, wqkv, qkv_b, qkvm,
                                                             3072, 1024);
  vt_prep<<<dim3(64, 2, 32), dim3(32, 8), 0, stream>>>(qkvm, vt);
  flash_kernel<<<768, 256, 0, stream>>>(qkvm, vt, attn, Op, ml);
  combine_kernel<<<256, 256, 0, stream>>>(Op, ml, attn);
  gemm_kernel<true, false><<<dim3(8, 32), 256, 0, stream>>>(attn, wproj, proj_b, out,
                                                            1024, 1024);
}

// Round 5
// 219.100 us; speedup vs baseline: 1.0943x; 1.0943x over previous
//
#include <hip/hip_runtime.h>
#include <cstdint>
#include <math.h>

#define DEV __device__ __forceinline__

typedef unsigned int u32;
typedef unsigned short u16;
typedef __attribute__((ext_vector_type(4))) float f32x4;
typedef __attribute__((ext_vector_type(4))) u32 u32x4;
typedef __attribute__((ext_vector_type(2))) u32 u32x2;
typedef __attribute__((ext_vector_type(8))) __bf16 bf16x8;

static_assert(sizeof(bf16x8) == 16, "bf16x8 must be 16B");

static constexpr int Tn = 2048, Cn = 1024;
static constexpr int Mrows = 2 * Tn;  // 4096
// Q scale: 1/sqrt(64)/TEMP * log2(e)  (softmax runs in exp2 domain)
static constexpr float QSCALE2 = 0.125f * 1.44269504088896f;

DEV u16 f2bf_rne(float f) {
  u32 u = __builtin_bit_cast(u32, f);
  u32 r = u + 0x7fffu + ((u >> 16) & 1u);
  return (u16)(r >> 16);
}
DEV float bf2f(u16 h) {
  u32 u = ((u32)h) << 16;
  return __builtin_bit_cast(float, u);
}
DEV u32 pack2bf(float a, float b) {  // a -> low16, b -> high16
  return (u32)f2bf_rne(a) | ((u32)f2bf_rne(b) << 16);
}
DEV float fexp2(float x) {
#if __has_builtin(__builtin_amdgcn_exp2f)
  return __builtin_amdgcn_exp2f(x);
#else
  return exp2f(x);
#endif
}

// async 16B global->LDS (wave-uniform base + lane*16 on the LDS side)
DEV void stage16(const void* g, void* l) {
#if __has_builtin(__builtin_amdgcn_global_load_lds)
  __builtin_amdgcn_global_load_lds(
      (__attribute__((address_space(1))) u32*)(uintptr_t)g,
      (__attribute__((address_space(3))) u32*)l, 16, 0, 0);
#else
  *(u32x4*)l = *(const u32x4*)g;
#endif
}

// ---------------- LayerNorm (fp32 in -> bf16 out) ----------------
__global__ __launch_bounds__(256) void ln_kernel(const float* __restrict__ x,
                                                 const float* __restrict__ sc,
                                                 const float* __restrict__ bi,
                                                 u16* __restrict__ xn) {
  int row = blockIdx.x;
  int t = threadIdx.x;
  const float* xr = x + (size_t)row * Cn;
  f32x4 v = *(const f32x4*)(xr + t * 4);
  float s = v.x + v.y + v.z + v.w;
  float s2 = v.x * v.x + v.y * v.y + v.z * v.z + v.w * v.w;
#pragma unroll
  for (int off = 1; off < 64; off <<= 1) {
    s += __shfl_xor(s, off);
    s2 += __shfl_xor(s2, off);
  }
  __shared__ float red[8];
  if ((t & 63) == 0) {
    red[(t >> 6) * 2] = s;
    red[(t >> 6) * 2 + 1] = s2;
  }
  __syncthreads();
  s = red[0] + red[2] + red[4] + red[6];
  s2 = red[1] + red[3] + red[5] + red[7];
  float mean = s * (1.0f / Cn);
  float var = s2 * (1.0f / Cn) - mean * mean;
  float rstd = rsqrtf(var + 1e-6f);
  f32x4 g = *(const f32x4*)(sc + t * 4);
  f32x4 b = *(const f32x4*)(bi + t * 4);
  u32 lo = pack2bf((v.x - mean) * rstd * g.x + b.x, (v.y - mean) * rstd * g.y + b.y);
  u32 hi = pack2bf((v.z - mean) * rstd * g.z + b.z, (v.w - mean) * rstd * g.w + b.w);
  u32x2 pack = {lo, hi};
  *(u32x2*)(xn + (size_t)row * Cn + t * 4) = pack;
}

// -------- transpose + cast both weights: fp32 [1024][Cc] -> bf16 [Cc][1024] --
__global__ __launch_bounds__(256) void transpose_cast2(const float* __restrict__ qkv_w,
                                                       u16* __restrict__ wqkv,
                                                       const float* __restrict__ proj_w,
                                                       u16* __restrict__ wproj) {
  __shared__ float tile[32][33];
  int bx = blockIdx.x;
  const float* src;
  u16* dst;
  int Cc;
  if (bx < 96) {
    src = qkv_w; dst = wqkv; Cc = 3072;
  } else {
    src = proj_w; dst = wproj; Cc = 1024; bx -= 96;
  }
  int tx = threadIdx.x, ty = threadIdx.y;
  int c0 = bx * 32, r0 = blockIdx.y * 32;
#pragma unroll
  for (int k = 0; k < 4; ++k)
    tile[ty + 8 * k][tx] = src[(size_t)(r0 + ty + 8 * k) * Cc + c0 + tx];
  __syncthreads();
#pragma unroll
  for (int k = 0; k < 4; ++k)
    dst[(size_t)(c0 + ty + 8 * k) * 1024 + r0 + tx] = f2bf_rne(tile[tx][ty + 8 * k]);
}

// ---- V^T prepass: qkvm V region [token][h*64+d] -> vt[bh][d][t] bf16 ----
__global__ __launch_bounds__(256) void vt_prep(const u16* __restrict__ qkvm,
                                               u16* __restrict__ vt) {
  __shared__ u16 tile[32][33];
  int bh = blockIdx.z;
  int b = bh >> 4, h = bh & 15;
  int t0 = blockIdx.x * 32, d0 = blockIdx.y * 32;
  int tx = threadIdx.x, ty = threadIdx.y;
#pragma unroll
  for (int k = 0; k < 4; ++k)
    tile[ty + 8 * k][tx] =
        qkvm[(size_t)(b * Tn + t0 + ty + 8 * k) * 3072 + 2 * Cn + h * 64 + d0 + tx];
  __syncthreads();
#pragma unroll
  for (int k = 0; k < 4; ++k)
    vt[((size_t)bh * 64 + d0 + ty + 8 * k) * 2048 + t0 + tx] = tile[tx][ty + 8 * k];
}

// ---------------- GEMM: A bf16 [M][K] x Bt bf16 [N][K] + bias -> C [M][N] ----
template <bool OUT_F32, bool QKV_SCALE>
__global__ __launch_bounds__(256, 3) void gemm_kernel(const u16* __restrict__ A,
                                                      const u16* __restrict__ Bt,
                                                      const float* __restrict__ bias,
                                                      void* __restrict__ Cout,
                                                      int Nsz, int Ksz) {
  __shared__ u16 As[128 * 32];
  __shared__ u16 Bs[128 * 32];
  int t = threadIdx.x;
  int l = t & 63, w = t >> 6;
  int quad = l >> 4, c16 = l & 15;
  int wm = w & 1, wn = w >> 1;
  int m0 = blockIdx.y * 128, n0 = blockIdx.x * 128;

  f32x4 acc[4][4];
#pragma unroll
  for (int mt = 0; mt < 4; ++mt)
#pragma unroll
    for (int nt = 0; nt < 4; ++nt) acc[mt][nt] = (f32x4){0.f, 0.f, 0.f, 0.f};

  for (int kk = 0; kk < Ksz; kk += 32) {
#pragma unroll
    for (int i = 0; i < 2; ++i) {
      int c = t + i * 256;
      int m = c >> 2, k8 = (c & 3) ^ ((m >> 1) & 3);
      stage16(A + (size_t)(m0 + m) * Ksz + kk + k8 * 8, (char*)As + c * 16);
    }
#pragma unroll
    for (int i = 0; i < 2; ++i) {
      int c = t + i * 256;
      int n = c >> 2, k8 = (c & 3) ^ ((n >> 1) & 3);
      stage16(Bt + (size_t)(n0 + n) * Ksz + kk + k8 * 8, (char*)Bs + c * 16);
    }
    __syncthreads();
    bf16x8 af[4], bf[4];
#pragma unroll
    for (int mt = 0; mt < 4; ++mt) {
      int m = wm * 64 + mt * 16 + c16;
      int LC = m * 4 + (quad ^ ((m >> 1) & 3));
      af[mt] = *(const bf16x8*)((const char*)As + LC * 16);
    }
#pragma unroll
    for (int nt = 0; nt < 4; ++nt) {
      int n = wn * 64 + nt * 16 + c16;
      int LC = n * 4 + (quad ^ ((n >> 1) & 3));
      bf[nt] = *(const bf16x8*)((const char*)Bs + LC * 16);
    }
#pragma unroll
    for (int mt = 0; mt < 4; ++mt)
#pragma unroll
      for (int nt = 0; nt < 4; ++nt)
        acc[mt][nt] = __builtin_amdgcn_mfma_f32_16x16x32_bf16(af[mt], bf[nt],
                                                              acc[mt][nt], 0, 0, 0);
    __syncthreads();
  }
  // epilogue: C/D layout col=lane&15, row=quad*4+reg
#pragma unroll
  for (int mt = 0; mt < 4; ++mt) {
    int row = m0 + wm * 64 + mt * 16 + quad * 4;
#pragma unroll
    for (int nt = 0; nt < 4; ++nt) {
      int col = n0 + wn * 64 + nt * 16 + c16;
      float bv = bias[col];
      float scale = (QKV_SCALE && col < 1024) ? QSCALE2 : 1.0f;
#pragma unroll
      for (int r = 0; r < 4; ++r) {
        float v = (acc[mt][nt][r] + bv) * scale;
        if (OUT_F32)
          ((float*)Cout)[(size_t)(row + r) * Nsz + col] = v;
        else
          ((u16*)Cout)[(size_t)(row + r) * Nsz + col] = f2bf_rne(v);
      }
    }
  }
}

// ---------------- causal flash attention, balanced chunks ----------------
// chunk table: {qt, k0, kcnt, half} sorted by kcnt desc; half<0 = direct write
__constant__ int4 chunk_tab[24] = {
    {15, 0, 8, 0}, {15, 8, 8, 1}, {14, 0, 8, 0}, {7, 0, 8, -1},
    {14, 8, 7, 1}, {13, 0, 7, 0}, {13, 7, 7, 1}, {12, 0, 7, 0}, {6, 0, 7, -1},
    {12, 7, 6, 1}, {11, 0, 6, 0}, {11, 6, 6, 1}, {10, 0, 6, 0}, {5, 0, 6, -1},
    {10, 6, 5, 1}, {9, 0, 5, 0}, {9, 5, 5, 1}, {8, 0, 5, 0}, {4, 0, 5, -1},
    {8, 5, 4, 1}, {3, 0, 4, -1},
    {2, 0, 3, -1},
    {1, 0, 2, -1},
    {0, 0, 1, -1}};

// qkv bf16 [4096][3072] (Q pre-scaled by 0.125*log2e), vt bf16 [32][64][2048]
// -> attn bf16 [4096][1024] (direct) or partials Op/ml. Softmax in exp2 domain.
// launch_bounds (256,2): VGPR cap 256 (compiler uses ~120, NO spill); 48KB LDS
// caps residency at 3 blocks/CU. (256,3) forced VGPR=84 -> 25MB scratch spill.
__global__ __launch_bounds__(256, 2) void flash_kernel(const u16* __restrict__ qkv,
                                                       const u16* __restrict__ vt,
                                                       u16* __restrict__ aout,
                                                       u16* __restrict__ Op,
                                                       float* __restrict__ ml) {
  int4 ck = chunk_tab[blockIdx.x >> 5];
  int bh = blockIdx.x & 31;
  int qt = ck.x, k0 = ck.y, kend = ck.y + ck.z, half = ck.w;
  int b = bh >> 4, h = bh & 15;
  int t = threadIdx.x, l = t & 63, w = t >> 6;
  int quad = l >> 4, c16 = l & 15;
  int q0 = qt * 128;

  __shared__ u16 Ks[128 * 64];  // [key][d] swizzled 16B chunks (16 KiB)
  __shared__ u16 Vs[64 * 128];  // [d][key] swizzled 16B chunks (16 KiB)
  __shared__ u16 Ps[128 * 64];  // [q][key-half] 16B chunks, wave-private (16 KiB)

  // Q fragments (B-operand layout), pre-scaled in GEMM epilogue
  bf16x8 qf[2][2];
#pragma unroll
  for (int nt = 0; nt < 2; ++nt)
#pragma unroll
    for (int ks = 0; ks < 2; ++ks)
      qf[nt][ks] = *(const bf16x8*)(qkv +
          (size_t)(b * Tn + q0 + w * 32 + nt * 16 + c16) * 3072 +
          h * 64 + ks * 32 + quad * 8);

  float mrow[2] = {-1e30f, -1e30f};
  float lrow[2] = {0.f, 0.f};
  f32x4 o[2][4];
#pragma unroll
  for (int mq = 0; mq < 2; ++mq)
#pragma unroll
    for (int dt = 0; dt < 4; ++dt) o[mq][dt] = (f32x4){0.f, 0.f, 0.f, 0.f};

  for (int kt = k0; kt < kend; ++kt) {
    // stage K [128key][64d] (async, swizzled)
#pragma unroll
    for (int i = 0; i < 4; ++i) {
      int c = t + i * 256;
      int key = c >> 3, d8 = (c & 7) ^ (key & 7);
      stage16(qkv + (size_t)(b * Tn + kt * 128 + key) * 3072 + Cn + h * 64 + d8 * 8,
              (char*)Ks + c * 16);
    }
    // stage V^T [64d][128key] (async, swizzled)
#pragma unroll
    for (int i = 0; i < 4; ++i) {
      int c = t + i * 256;
      int d = c >> 4, k8 = (c & 15) ^ (d & 15);
      stage16(vt + ((size_t)bh * 64 + d) * 2048 + kt * 128 + k8 * 8,
              (char*)Vs + c * 16);
    }
    __syncthreads();

    // S^T = K . Q^T  (A=K from LDS, B=Q^T from regs); m=key, n=q
    f32x4 s[8][2];
#pragma unroll
    for (int mt = 0; mt < 8; ++mt)
#pragma unroll
      for (int nt = 0; nt < 2; ++nt) s[mt][nt] = (f32x4){0.f, 0.f, 0.f, 0.f};
#pragma unroll
    for (int mt = 0; mt < 8; ++mt) {
#pragma unroll
      for (int ks = 0; ks < 2; ++ks) {
        int key = mt * 16 + c16;
        int d8 = ks * 4 + quad;
        int LC = key * 8 + (d8 ^ (key & 7));
        bf16x8 kf = *(const bf16x8*)((const char*)Ks + LC * 16);
#pragma unroll
        for (int nt = 0; nt < 2; ++nt)
          s[mt][nt] = __builtin_amdgcn_mfma_f32_16x16x32_bf16(kf, qf[nt][ks],
                                                              s[mt][nt], 0, 0, 0);
      }
    }
    // diagonal causal mask
    if (kt == qt) {
#pragma unroll
      for (int mt = 0; mt < 8; ++mt)
#pragma unroll
        for (int nt = 0; nt < 2; ++nt)
#pragma unroll
          for (int r = 0; r < 4; ++r) {
            int key = kt * 128 + mt * 16 + quad * 4 + r;
            int q = q0 + w * 32 + nt * 16 + c16;
            if (key > q) s[mt][nt][r] = -1e30f;
          }
    }
    // online softmax, exp2 domain (stats per q = c16, replicated over quads)
    float alph[2];
#pragma unroll
    for (int nt = 0; nt < 2; ++nt) {
      float rm = -1e30f;
#pragma unroll
      for (int mt = 0; mt < 8; ++mt)
#pragma unroll
        for (int r = 0; r < 4; ++r) rm = fmaxf(rm, s[mt][nt][r]);
      rm = fmaxf(rm, __shfl_xor(rm, 16));
      rm = fmaxf(rm, __shfl_xor(rm, 32));
      float mnew = fmaxf(mrow[nt], rm);
      alph[nt] = fexp2(mrow[nt] - mnew);
      mrow[nt] = mnew;
      float rs = 0.f;
#pragma unroll
      for (int mt = 0; mt < 8; ++mt)
#pragma unroll
        for (int r = 0; r < 4; ++r) {
          float e = fexp2(s[mt][nt][r] - mnew);
          s[mt][nt][r] = e;
          rs += e;
        }
      rs += __shfl_xor(rs, 16);
      rs += __shfl_xor(rs, 32);
      lrow[nt] = lrow[nt] * alph[nt] + rs;
    }
    // rescale O by alpha (alpha lives per q=c16; O rows are q=quad*4+r)
#pragma unroll
    for (int mq = 0; mq < 2; ++mq)
#pragma unroll
      for (int r = 0; r < 4; ++r) {
        float a = __shfl(alph[mq], quad * 4 + r);
#pragma unroll
        for (int dt = 0; dt < 4; ++dt) o[mq][dt][r] *= a;
      }
    // PV in two key-halves through 16KB wave-private Ps (same-wave DS is in-order)
#pragma unroll
    for (int ksh = 0; ksh < 2; ++ksh) {
#pragma unroll
      for (int mtl = 0; mtl < 4; ++mtl) {
        int mt = ksh * 4 + mtl;
#pragma unroll
        for (int nt = 0; nt < 2; ++nt) {
          int q = w * 32 + nt * 16 + c16;
          int c8 = mtl * 2 + (quad >> 1);
          u32x2 pk = {pack2bf(s[mt][nt][0], s[mt][nt][1]),
                      pack2bf(s[mt][nt][2], s[mt][nt][3])};
          *(u32x2*)((char*)Ps + q * 128 + ((c8 ^ (c16 & 7)) * 16) + (quad & 1) * 8) =
              pk;
        }
      }
#pragma unroll
      for (int ksl = 0; ksl < 2; ++ksl) {
        int ks = ksh * 2 + ksl;
        bf16x8 pa[2];
#pragma unroll
        for (int mq = 0; mq < 2; ++mq) {
          int q = w * 32 + mq * 16 + c16;
          int c8 = ksl * 4 + quad;
          pa[mq] = *(const bf16x8*)((const char*)Ps + q * 128 +
                                    ((c8 ^ (c16 & 7)) * 16));
        }
#pragma unroll
        for (int dt = 0; dt < 4; ++dt) {
          int d = dt * 16 + c16;
          int vc = d * 16 + ((ks * 4 + quad) ^ (d & 15));
          bf16x8 vf = *(const bf16x8*)((const char*)Vs + vc * 16);
#pragma unroll
          for (int mq = 0; mq < 2; ++mq)
            o[mq][dt] = __builtin_amdgcn_mfma_f32_16x16x32_bf16(pa[mq], vf,
                                                                o[mq][dt], 0, 0, 0);
        }
      }
    }
    __syncthreads();
  }

  float linv[2] = {1.0f / lrow[0], 1.0f / lrow[1]};
  if (half < 0) {
    // direct output
#pragma unroll
    for (int mq = 0; mq < 2; ++mq)
#pragma unroll
      for (int r = 0; r < 4; ++r) {
        float li = __shfl(linv[mq], quad * 4 + r);
        int q = q0 + w * 32 + mq * 16 + quad * 4 + r;
#pragma unroll
        for (int dt = 0; dt < 4; ++dt)
          aout[(size_t)(b * Tn + q) * 1024 + h * 64 + dt * 16 + c16] =
              f2bf_rne(o[mq][dt][r] * li);
      }
  } else {
    // partial: normalized O + (m, l) per row (m in log2 domain)
    int ps = ((qt - 8) * 32 + bh) * 2 + half;
#pragma unroll
    for (int mq = 0; mq < 2; ++mq)
#pragma unroll
      for (int r = 0; r < 4; ++r) {
        float li = __shfl(linv[mq], quad * 4 + r);
        int qr = w * 32 + mq * 16 + quad * 4 + r;
#pragma unroll
        for (int dt = 0; dt < 4; ++dt)
          Op[((size_t)ps * 128 + qr) * 64 + dt * 16 + c16] =
              f2bf_rne(o[mq][dt][r] * li);
      }
    if (quad == 0) {
#pragma unroll
      for (int nt = 0; nt < 2; ++nt) {
        int qr = w * 32 + nt * 16 + c16;
        ml[((size_t)ps * 128 + qr) * 2] = mrow[nt];
        ml[((size_t)ps * 128 + qr) * 2 + 1] = lrow[nt];
      }
    }
  }
}

// ---------------- combine split partials (m in log2 domain) ----------------
__global__ __launch_bounds__(256) void combine_kernel(const u16* __restrict__ Op,
                                                      const float* __restrict__ ml,
                                                      u16* __restrict__ aout) {
  int qt = 8 + (blockIdx.x >> 5);
  int bh = blockIdx.x & 31;
  int b = bh >> 4, h = bh & 15;
  int ps0 = ((qt - 8) * 32 + bh) * 2;
  int d = threadIdx.x & 63, rq = threadIdx.x >> 6;
  for (int r = 0; r < 32; ++r) {
    int row = rq * 32 + r;
    float m0 = ml[((size_t)ps0 * 128 + row) * 2];
    float l0 = ml[((size_t)ps0 * 128 + row) * 2 + 1];
    float m1 = ml[((size_t)(ps0 + 1) * 128 + row) * 2];
    float l1 = ml[((size_t)(ps0 + 1) * 128 + row) * 2 + 1];
    float M = fmaxf(m0, m1);
    float w0 = fexp2(m0 - M) * l0, w1 = fexp2(m1 - M) * l1;
    float inv = 1.0f / (w0 + w1);
    float o0 = bf2f(Op[((size_t)ps0 * 128 + row) * 64 + d]);
    float o1 = bf2f(Op[((size_t)(ps0 + 1) * 128 + row) * 64 + d]);
    aout[(size_t)(b * Tn + qt * 128 + row) * 1024 + h * 64 + d] =
        f2bf_rne((w0 * o0 + w1 * o1) * inv);
  }
}

extern "C" void kernel_launch(void* const* d_in, const int* in_sizes, int n_in,
                              void* d_out, int out_size, void* d_ws, size_t ws_size,
                              hipStream_t stream) {
  const float* x = (const float*)d_in[0];
  // d_in[1] = causal mask: tril, implemented analytically — never read
  const float* ln_s = (const float*)d_in[2];
  const float* ln_b = (const float*)d_in[3];
  const float* qkv_w = (const float*)d_in[4];
  const float* qkv_b = (const float*)d_in[5];
  const float* proj_w = (const float*)d_in[6];
  const float* proj_b = (const float*)d_in[7];
  float* out = (float*)d_out;
  char* ws = (char*)d_ws;

  u16* xn = (u16*)ws;                       // 8 MiB  [4096][1024]
  u16* wqkv = (u16*)(ws + (8ull << 20));    // 6 MiB  [3072][1024]
  u16* wproj = (u16*)(ws + (14ull << 20));  // 2 MiB  [1024][1024]
  u16* qkvm = (u16*)(ws + (16ull << 20));   // 24 MiB [4096][3072]
  u16* attn = (u16*)(ws + (40ull << 20));   // 8 MiB  [4096][1024]
  u16* vt = (u16*)(ws + (48ull << 20));     // 8 MiB  [32][64][2048]
  // partials alias xn/wqkv (dead after QKV GEMM):
  u16* Op = (u16*)ws;                       // 8 MiB  [512][128][64] bf16
  float* ml = (float*)(ws + (8ull << 20));  // 512 KiB [512][128][2] f32

  ln_kernel<<<Mrows, 256, 0, stream>>>(x, ln_s, ln_b, xn);
  transpose_cast2<<<dim3(128, 32), dim3(32, 8), 0, stream>>>(qkv_w, wqkv, proj_w,
                                                             wproj);
  gemm_kernel<false, true><<<dim3(24, 32), 256, 0, stream>>>(xn, wqkv, qkv_b, qkvm,
                                                             3072, 1024);
  vt_prep<<<dim3(64, 2, 32), dim3(32, 8), 0, stream>>>(qkvm, vt);
  flash_kernel<<<768, 256, 0, stream>>>(qkvm, vt, attn, Op, ml);
  combine_kernel<<<256, 256, 0, stream>>>(Op, ml, attn);
  gemm_kernel<true, false><<<dim3(8, 32), 256, 0, stream>>>(attn, wproj, proj_b, out,
                                                            1024, 1024);
}